// Round 19
// baseline (389.728 us; speedup 1.0000x reference)
//
#include <hip/hip_runtime.h>
#include <hip/hip_bf16.h>

#define H 128
#define NGRAPH 64
#define NLAYERS 2
#define TMM 64          // rows per MLP block
#define TP 136          // LDS row stride in bf16 (pad 8)
#define BSH 8           // bucket shift: 256 nodes per bucket
#define MAXB 512        // max buckets (n <= 131072)

typedef short short8 __attribute__((ext_vector_type(8)));
typedef float floatx4 __attribute__((ext_vector_type(4)));
typedef float floatx2 __attribute__((ext_vector_type(2)));

static __device__ __forceinline__ unsigned short f2bf(float v) {
    __hip_bfloat16 b = __float2bfloat16(v);
    return *(unsigned short*)&b;
}
static __device__ __forceinline__ float bf2f(unsigned short u) {
    return __uint_as_float(((unsigned int)u) << 16);
}
// pack 4 f32 -> 4 fp8(e4m3) bytes
static __device__ __forceinline__ int pack4_fp8(float a, float b, float c, float d) {
    int p = __builtin_amdgcn_cvt_pk_fp8_f32(a, b, 0, false);
    p = __builtin_amdgcn_cvt_pk_fp8_f32(c, d, p, true);
    return p;
}

// ------- encoder: h = bf16(x*w+b); fp8 shadow h8 = fp8(h + edge_bias) -------
__global__ void enc_kernel(const float* __restrict__ x, const float* __restrict__ w,
                           const float* __restrict__ b, const float* __restrict__ eb,
                           unsigned short* __restrict__ h,
                           unsigned char* __restrict__ h8, int n) {
    int t = blockIdx.x * blockDim.x + threadIdx.x;
    int i = t >> 5;            // node
    int c = (t & 31) << 2;     // feature*4
    if (i >= n) return;
    float xv = x[i];
    float4 wv = *(const float4*)(w + c);
    float4 bv = *(const float4*)(b + c);
    float4 ev = *(const float4*)(eb + c);
    float4 o;
    o.x = xv * wv.x + bv.x;
    o.y = xv * wv.y + bv.y;
    o.z = xv * wv.z + bv.z;
    o.w = xv * wv.w + bv.w;
    ushort4 ob;
    ob.x = f2bf(o.x); ob.y = f2bf(o.y); ob.z = f2bf(o.z); ob.w = f2bf(o.w);
    *(ushort4*)(h + (size_t)i * H + c) = ob;
    *(int*)(h8 + (size_t)i * H + c) =
        pack4_fp8(o.x + ev.x, o.y + ev.y, o.z + ev.z, o.w + ev.w);
}

// ------- prep: weights to bf16 fragment-major + BN fold (merged) -------
__global__ void prep_kernel(const float* __restrict__ w1, const float* __restrict__ w2,
                            unsigned short* __restrict__ w1f, unsigned short* __restrict__ w2f,
                            const float* __restrict__ b2, const float* __restrict__ g,
                            const float* __restrict__ bt, const float* __restrict__ mn,
                            const float* __restrict__ vr,
                            float* __restrict__ scb, float* __restrict__ shb) {
    int idx = blockIdx.x * blockDim.x + threadIdx.x;   // 2*128*128
    int l = idx >> 14;
    int r = idx & 16383;
    int nn = r >> 7;      // output col = B row
    int kk = r & 127;     // k index
    int ct = nn >> 4, m = nn & 15;
    int kbi = kk >> 5, q = (kk >> 3) & 3, j = kk & 7;
    int fo = l * 16384 + ct * 2048 + kbi * 512 + (q * 16 + m) * 8 + j;
    w1f[fo] = f2bf(w1[(size_t)l * 16384 + kk * 128 + nn]);
    w2f[fo] = f2bf(w2[(size_t)l * 16384 + kk * 128 + nn]);
    if (idx < NLAYERS * H) {
        float sc = g[idx] * rsqrtf(vr[idx] + 1e-5f);
        scb[idx] = sc;
        shb[idx] = (b2[idx] - mn[idx]) * sc + bt[idx];
    }
}

// ---- bucket histogram: LDS-aggregated counts of edges per 256-node bucket ----
__global__ __launch_bounds__(256) void histB_kernel(const int* __restrict__ ei,
                                                    int* __restrict__ bcnt, int ne) {
    __shared__ int hist[MAXB];
    const int t = threadIdx.x;
    const int e0 = blockIdx.x * 4096;
    for (int k = t; k < MAXB; k += 256) hist[k] = 0;
    __syncthreads();
    #pragma unroll
    for (int k = 0; k < 16; ++k) {
        int e = e0 + k * 256 + t;
        if (e < ne) atomicAdd(&hist[ei[ne + e] >> BSH], 1);
    }
    __syncthreads();
    for (int b = t; b < MAXB; b += 256) {
        int c = hist[b];
        if (c > 0) atomicAdd(&bcnt[b], c);
    }
}

// ---- bucket scan: exclusive prefix over <=512 bucket counts (one block) ----
__global__ __launch_bounds__(256) void scanB_kernel(const int* __restrict__ bcnt,
                                                    int* __restrict__ bstart,
                                                    int* __restrict__ start,
                                                    int nbuck, int n, int ne) {
    __shared__ int wsum[4];
    const int t = threadIdx.x;
    const int lane = t & 63;
    const int wid = t >> 6;
    int i0 = 2 * t, i1 = 2 * t + 1;
    int v0 = (i0 < nbuck) ? bcnt[i0] : 0;
    int v1 = (i1 < nbuck) ? bcnt[i1] : 0;
    int s = v0 + v1;
    int incl = s;
    #pragma unroll
    for (int off = 1; off < 64; off <<= 1) {
        int u = __shfl_up(incl, off, 64);
        if (lane >= off) incl += u;
    }
    if (lane == 63) wsum[wid] = incl;
    __syncthreads();
    int woff = 0;
    #pragma unroll
    for (int k = 0; k < 4; ++k) if (k < wid) woff += wsum[k];
    int excl = woff + incl - s;
    if (i0 < nbuck) bstart[i0] = excl;
    if (i1 < nbuck) bstart[i1] = excl + v0;
    if (t == 0) { bstart[nbuck] = ne; start[n] = ne; }
}

// ---- sort phase A: bin edges into buckets, block-coalesced runs ----
// entry: x = src, y = (attr_bf16 << 16) | local_dst(8b)
__global__ __launch_bounds__(256) void binA_kernel(
    const int* __restrict__ ei, const float* __restrict__ ea,
    const int* __restrict__ bstart, int* __restrict__ bcursor,
    int2* __restrict__ sedge2, int ne, int nbuck) {
    __shared__ int hist[MAXB];
    __shared__ int gpos[MAXB];
    const int t = threadIdx.x;
    const int e0 = blockIdx.x * 4096;
    for (int k = t; k < MAXB; k += 256) hist[k] = 0;
    __syncthreads();
    int dsts[16];
    #pragma unroll
    for (int k = 0; k < 16; ++k) {
        int e = e0 + k * 256 + t;
        int d = (e < ne) ? ei[ne + e] : -1;
        dsts[k] = d;
        if (d >= 0) atomicAdd(&hist[d >> BSH], 1);
    }
    __syncthreads();
    for (int b = t; b < nbuck; b += 256) {
        int c = hist[b];
        gpos[b] = (c > 0) ? (bstart[b] + atomicAdd(&bcursor[b], c)) : 0;
    }
    __syncthreads();
    for (int k = t; k < MAXB; k += 256) hist[k] = 0;   // reuse as local cursor
    __syncthreads();
    #pragma unroll
    for (int k = 0; k < 16; ++k) {
        int d = dsts[k];
        if (d >= 0) {
            int e = e0 + k * 256 + t;
            int b = d >> BSH;
            int idx = atomicAdd(&hist[b], 1);
            int2 p;
            p.x = ei[e];
            p.y = ((int)f2bf(ea[e]) << 16) | (d & ((1 << BSH) - 1));
            sedge2[gpos[b] + idx] = p;
        }
    }
}

// ---- sort phase B: per-bucket node layout + exact scatter (one block/bucket) ----
__global__ __launch_bounds__(256) void binB_kernel(
    const int2* __restrict__ sedge2, const int* __restrict__ bstart,
    int2* __restrict__ sedge, int* __restrict__ start, int n) {
    __shared__ int nhist[1 << BSH];
    __shared__ int nstart_s[1 << BSH];
    __shared__ int wsum[4];
    const int node0 = blockIdx.x << BSH;
    const int t = threadIdx.x;
    const int lane = t & 63;
    const int wid = t >> 6;
    nhist[t] = 0;
    __syncthreads();
    int s0 = bstart[blockIdx.x];
    int s1 = bstart[blockIdx.x + 1];
    for (int i = s0 + t; i < s1; i += 256)
        atomicAdd(&nhist[sedge2[i].y & ((1 << BSH) - 1)], 1);
    __syncthreads();
    int v = nhist[t];
    int incl = v;
    #pragma unroll
    for (int off = 1; off < 64; off <<= 1) {
        int u = __shfl_up(incl, off, 64);
        if (lane >= off) incl += u;
    }
    if (lane == 63) wsum[wid] = incl;
    __syncthreads();
    int woff = 0;
    #pragma unroll
    for (int k = 0; k < 4; ++k) if (k < wid) woff += wsum[k];
    int excl = woff + incl - v;
    nstart_s[t] = excl;
    if (node0 + t < n) start[node0 + t] = s0 + excl;
    nhist[t] = 0;       // reuse as per-node cursor
    __syncthreads();
    for (int i = s0 + t; i < s1; i += 256) {
        int2 p = sedge2[i];
        int ld = p.y & ((1 << BSH) - 1);
        int idx = atomicAdd(&nhist[ld], 1);
        p.y = (int)((unsigned)p.y & 0xffff0000u);   // attr bf16 only
        sedge[s0 + nstart_s[ld] + idx] = p;
    }
}

// ---- fused layer: z = (1+eps)h + sum relu(h8[src]+a*ew)  (gathered in-kernel,
// straight into the wave-private LDS tile), then MFMA MLP, BN, relu, h out.
// Layer 0 additionally emits the fp8 shadow h8 = fp8(h + eb).
__global__ __launch_bounds__(256) void layer_kernel(
    unsigned short* __restrict__ h, const unsigned char* __restrict__ h8,
    const int* __restrict__ start, const int2* __restrict__ sedge,
    const float* __restrict__ ew, const float* __restrict__ epsp, int layer,
    const unsigned short* __restrict__ w1f, const float* __restrict__ b1,
    const unsigned short* __restrict__ w2f,
    const float* __restrict__ scb, const float* __restrict__ shb,
    unsigned char* __restrict__ h8out, const float* __restrict__ eb, int n) {
    __shared__ unsigned short zs[4][16 * TP];   // per-wave z tile / output tile
    __shared__ unsigned short ts[4][16 * TP];   // per-wave t tile
    const int tid = threadIdx.x;
    const int wid = tid >> 6;
    const int lane = tid & 63;
    const int m = lane & 15;     // A row within 16 / B col
    const int q = lane >> 4;     // quad
    const int row0 = blockIdx.x * TMM + wid * 16;
    const unsigned c = (unsigned)lane << 1;

    // ---- gather phase: compute 16 z rows into wave-private LDS ----
    unsigned short* zw = zs[wid];
    {
        float2 wv = *(const float2*)(ew + c);
        float ev = 1.0f + epsp[layer];
        for (int r = 0; r < 16; ++r) {
            int node = row0 + r;
            ushort2 p = make_ushort2(0, 0);
            if (node < n) {
                float2 acc = make_float2(0.f, 0.f);
                int s0 = start[node], s1 = start[node + 1];
                int j = s0;
                for (; j + 16 <= s1; j += 16) {
                    int2 e[16];
                    unsigned short v8[16];
                    #pragma unroll
                    for (int k = 0; k < 16; ++k) e[k] = sedge[j + k];
                    #pragma unroll
                    for (int k = 0; k < 16; ++k)
                        v8[k] = *(const unsigned short*)(h8 + (((unsigned)e[k].x << 7) + c));
                    #pragma unroll
                    for (int k = 0; k < 16; ++k) {
                        float a = __int_as_float(e[k].y);
                        floatx2 hv = __builtin_amdgcn_cvt_pk_f32_fp8((int)v8[k], false);
                        acc.x += fmaxf(fmaf(a, wv.x, hv.x), 0.f);
                        acc.y += fmaxf(fmaf(a, wv.y, hv.y), 0.f);
                    }
                }
                if (j + 8 <= s1) {
                    int2 e[8];
                    unsigned short v8[8];
                    #pragma unroll
                    for (int k = 0; k < 8; ++k) e[k] = sedge[j + k];
                    #pragma unroll
                    for (int k = 0; k < 8; ++k)
                        v8[k] = *(const unsigned short*)(h8 + (((unsigned)e[k].x << 7) + c));
                    #pragma unroll
                    for (int k = 0; k < 8; ++k) {
                        float a = __int_as_float(e[k].y);
                        floatx2 hv = __builtin_amdgcn_cvt_pk_f32_fp8((int)v8[k], false);
                        acc.x += fmaxf(fmaf(a, wv.x, hv.x), 0.f);
                        acc.y += fmaxf(fmaf(a, wv.y, hv.y), 0.f);
                    }
                    j += 8;
                }
                if (j < s1) {
                    int2 e[8];
                    unsigned short v8[8];
                    #pragma unroll
                    for (int k = 0; k < 8; ++k) {
                        int idx = j + k;
                        e[k] = sedge[idx < s1 ? idx : (s1 - 1)];
                    }
                    #pragma unroll
                    for (int k = 0; k < 8; ++k)
                        v8[k] = *(const unsigned short*)(h8 + (((unsigned)e[k].x << 7) + c));
                    #pragma unroll
                    for (int k = 0; k < 8; ++k) {
                        float valid = (j + k < s1) ? 1.f : 0.f;
                        float a = __int_as_float(e[k].y);
                        floatx2 hv = __builtin_amdgcn_cvt_pk_f32_fp8((int)v8[k], false);
                        acc.x += valid * fmaxf(fmaf(a, wv.x, hv.x), 0.f);
                        acc.y += valid * fmaxf(fmaf(a, wv.y, hv.y), 0.f);
                    }
                }
                ushort2 hv = *(const ushort2*)(h + (size_t)node * H + c);
                p.x = f2bf(fmaf(ev, bf2f(hv.x), acc.x));
                p.y = f2bf(fmaf(ev, bf2f(hv.y), acc.y));
            }
            *(ushort2*)(zw + r * TP + c) = p;
        }
    }

    // ---------- GEMM1: t = relu(z @ w1 + b1) ----------
    floatx4 acc[8];
    #pragma unroll
    for (int ct = 0; ct < 8; ++ct) acc[ct] = (floatx4)(0.f);

    #pragma unroll
    for (int kbi = 0; kbi < 4; ++kbi) {
        short8 a = *(const short8*)(zw + m * TP + kbi * 32 + q * 8);
        #pragma unroll
        for (int ct = 0; ct < 8; ++ct) {
            short8 b = *(const short8*)(w1f + ct * 2048 + kbi * 512 + lane * 8);
            acc[ct] = __builtin_amdgcn_mfma_f32_16x16x32_bf16(a, b, acc[ct], 0, 0, 0);
        }
    }
    unsigned short* tw = ts[wid];
    #pragma unroll
    for (int ct = 0; ct < 8; ++ct) {
        float bb = b1[ct * 16 + m];
        #pragma unroll
        for (int r = 0; r < 4; ++r) {
            float v = fmaxf(acc[ct][r] + bb, 0.f);
            tw[(q * 4 + r) * TP + ct * 16 + m] = f2bf(v);
        }
    }

    // ---------- GEMM2: z2 = t @ w2, then folded BN (sc,sh) + relu ----------
    floatx4 acc2[8];
    #pragma unroll
    for (int ct = 0; ct < 8; ++ct) acc2[ct] = (floatx4)(0.f);

    #pragma unroll
    for (int kbi = 0; kbi < 4; ++kbi) {
        short8 a = *(const short8*)(tw + m * TP + kbi * 32 + q * 8);
        #pragma unroll
        for (int ct = 0; ct < 8; ++ct) {
            short8 b = *(const short8*)(w2f + ct * 2048 + kbi * 512 + lane * 8);
            acc2[ct] = __builtin_amdgcn_mfma_f32_16x16x32_bf16(a, b, acc2[ct], 0, 0, 0);
        }
    }
    // epilogue2: stage C into wave-private LDS tile (reuse zw), coalesced store
    #pragma unroll
    for (int ct = 0; ct < 8; ++ct) {
        int col = ct * 16 + m;
        float scv = scb[col];
        float shv = shb[col];
        #pragma unroll
        for (int r = 0; r < 4; ++r) {
            float v = fmaxf(fmaf(acc2[ct][r], scv, shv), 0.f);
            zw[(q * 4 + r) * TP + col] = f2bf(v);
        }
    }
    {
        unsigned short* hg = h + (size_t)row0 * H;
        #pragma unroll
        for (int i = 0; i < 4; ++i) {
            int idx = i * 64 + lane;
            int r = idx >> 4;
            int c8 = (idx & 15) << 3;
            if (row0 + r < n)
                *(short8*)(hg + r * H + c8) = *(const short8*)(zw + r * TP + c8);
        }
    }
    // fused cast (layer 0 only): h8 = fp8(h + eb), coalesced 8 B/lane
    if (h8out) {
        unsigned char* h8g = h8out + (size_t)row0 * H;
        #pragma unroll
        for (int i = 0; i < 4; ++i) {
            int idx = i * 64 + lane;
            int r = idx >> 4;
            int c8 = (idx & 15) << 3;
            if (row0 + r < n) {
                const unsigned short* src = zw + r * TP + c8;
                float4 e0 = *(const float4*)(eb + c8);
                float4 e1 = *(const float4*)(eb + c8 + 4);
                int2 pk;
                pk.x = pack4_fp8(bf2f(src[0]) + e0.x, bf2f(src[1]) + e0.y,
                                 bf2f(src[2]) + e0.z, bf2f(src[3]) + e0.w);
                pk.y = pack4_fp8(bf2f(src[4]) + e1.x, bf2f(src[5]) + e1.y,
                                 bf2f(src[6]) + e1.z, bf2f(src[7]) + e1.w);
                *(int2*)(h8g + r * H + c8) = pk;
            }
        }
    }
}

// ---- graph boundaries from sorted batch: gstart[g] = first node of graph g ----
__global__ void gbound_kernel(const int* __restrict__ batch, int* __restrict__ gstart, int n) {
    int i = blockIdx.x * blockDim.x + threadIdx.x;
    if (i >= n) return;
    int b = batch[i];
    if (i == 0) {
        for (int g = 0; g <= b; ++g) gstart[g] = 0;
    } else {
        int p = batch[i - 1];
        for (int g = p + 1; g <= b; ++g) gstart[g] = i;
    }
    if (i == n - 1) {
        for (int g = b + 1; g <= NGRAPH; ++g) gstart[g] = n;
    }
}

// ---- global mean pool: segmented gather of bf16 h, LDS reduce, few atomics ----
__global__ __launch_bounds__(256) void pool_kernel(const unsigned short* __restrict__ h,
                                                   const int* __restrict__ gstart,
                                                   float* __restrict__ sums) {
    __shared__ float4 buf[8][32];
    const int g = blockIdx.x;       // graph
    const int split = blockIdx.y;   // 0..7
    const int t = threadIdx.x;
    const int c32 = t & 31;
    const int c = c32 << 2;
    const int r = t >> 5;           // 0..7
    int s0 = gstart[g], s1 = gstart[g + 1];
    int len = s1 - s0;
    int chunk = (len + 7) >> 3;
    int a = s0 + split * chunk;
    int b = min(a + chunk, s1);
    float4 acc = make_float4(0.f, 0.f, 0.f, 0.f);
    for (int i = a + r; i < b; i += 8) {
        ushort4 v = *(const ushort4*)(h + (size_t)i * H + c);
        acc.x += bf2f(v.x); acc.y += bf2f(v.y); acc.z += bf2f(v.z); acc.w += bf2f(v.w);
    }
    buf[r][c32] = acc;
    __syncthreads();
    if (r == 0) {
        float4 s = buf[0][c32];
        #pragma unroll
        for (int k = 1; k < 8; ++k) {
            float4 v = buf[k][c32];
            s.x += v.x; s.y += v.y; s.z += v.z; s.w += v.w;
        }
        float* sp = sums + (size_t)g * H + c;
        atomicAdd(sp + 0, s.x);
        atomicAdd(sp + 1, s.y);
        atomicAdd(sp + 2, s.z);
        atomicAdd(sp + 3, s.w);
    }
}

// ---------------- classifier: sigmoid(relu(g@w1+b1)@w2+b2) ----------------
__global__ void cls_kernel(const float* __restrict__ sums, const int* __restrict__ gstart,
                           const float* __restrict__ w1, const float* __restrict__ b1,
                           const float* __restrict__ w2, const float* __restrict__ b2,
                           float* __restrict__ out) {
    int g = blockIdx.x;     // 64 graphs
    int m = threadIdx.x;    // 64 mids
    float cnt = (float)(gstart[g + 1] - gstart[g]);
    float inv = 1.0f / fmaxf(cnt, 1.0f);
    float acc = 0.f;
    for (int k = 0; k < H; ++k) {
        float gk = sums[(size_t)g * H + k] * inv;
        acc += gk * w1[(size_t)k * 64 + m];
    }
    float tm = fmaxf(acc + b1[m], 0.f);
    float p = tm * w2[m];
    #pragma unroll
    for (int off = 32; off > 0; off >>= 1) p += __shfl_down(p, off, 64);
    if (m == 0) out[g] = 1.f / (1.f + expf(-(p + b2[0])));
}

extern "C" void kernel_launch(void* const* d_in, const int* in_sizes, int n_in,
                              void* d_out, int out_size, void* d_ws, size_t ws_size,
                              hipStream_t stream) {
    const float* x      = (const float*)d_in[0];
    const int*   ei     = (const int*)d_in[1];
    const float* ea     = (const float*)d_in[2];
    const int*   batch  = (const int*)d_in[3];
    const float* enc_w  = (const float*)d_in[4];
    const float* enc_b  = (const float*)d_in[5];
    const float* edge_w = (const float*)d_in[6];
    const float* edge_b = (const float*)d_in[7];
    const float* eps    = (const float*)d_in[8];
    const float* mlp_w1 = (const float*)d_in[9];
    const float* mlp_b1 = (const float*)d_in[10];
    const float* mlp_w2 = (const float*)d_in[11];
    const float* mlp_b2 = (const float*)d_in[12];
    const float* bn_g   = (const float*)d_in[13];
    const float* bn_b   = (const float*)d_in[14];
    const float* bn_m   = (const float*)d_in[15];
    const float* bn_v   = (const float*)d_in[16];
    const float* cls_w1 = (const float*)d_in[17];
    const float* cls_b1 = (const float*)d_in[18];
    const float* cls_w2 = (const float*)d_in[19];
    const float* cls_b2 = (const float*)d_in[20];
    float* out = (float*)d_out;

    const int n = in_sizes[0];        // 100000
    const int ne = in_sizes[2];       // 1600000
    const int nbuck = (n + (1 << BSH) - 1) >> BSH;  // 256-node buckets

    // workspace layout (regions kept 16B-aligned).
    // sums, bcnt, bcursor are CONTIGUOUS so one memset zeroes all three.
    unsigned short* hb  = (unsigned short*)d_ws;                    // N*H bf16
    unsigned char* h8   = (unsigned char*)(hb + (size_t)n * H);     // N*H fp8
    float* sums         = (float*)(h8 + (size_t)n * H);             // G*H
    int*   bcnt         = (int*)(sums + (size_t)NGRAPH * H);        // MAXB
    int*   bcursor      = bcnt + MAXB;                              // MAXB
    int*   bstart       = bcursor + MAXB;                           // MAXB+4
    int*   gstart       = bstart + MAXB + 4;                        // G+4
    int*   start        = gstart + NGRAPH + 4;                      // N+4
    float* scb          = (float*)(start + n + 4);                  // 2*128
    float* shb          = scb + NLAYERS * H;                        // 2*128
    unsigned short* w1f = (unsigned short*)(shb + NLAYERS * H);     // 2*128*128
    unsigned short* w2f = w1f + 2 * 16384;                          // 2*128*128
    int2*  sedge2       = (int2*)(w2f + 2 * 16384);                 // E (binned)
    int2*  sedge        = sedge2 + ne;                              // E (sorted)

    // one memset covers sums + bcnt + bcursor (contiguous)
    hipMemsetAsync(sums, 0, ((size_t)NGRAPH * H + 2 * MAXB) * sizeof(int), stream);

    // weight prep (bf16 fragment-major) + BN fold — once per call
    prep_kernel<<<128, 256, 0, stream>>>(mlp_w1, mlp_w2, w1f, w2f,
                                         mlp_b2, bn_g, bn_b, bn_m, bn_v, scb, shb);

    // ---- bucket-granular counting sort of edges by dst ----
    histB_kernel<<<(ne + 4095) / 4096, 256, 0, stream>>>(ei, bcnt, ne);
    scanB_kernel<<<1, 256, 0, stream>>>(bcnt, bstart, start, nbuck, n, ne);
    binA_kernel<<<(ne + 4095) / 4096, 256, 0, stream>>>(ei, ea, bstart, bcursor, sedge2, ne, nbuck);
    binB_kernel<<<nbuck, 256, 0, stream>>>(sedge2, bstart, sedge, start, n);

    // graph boundaries for pooling
    gbound_kernel<<<(n + 255) / 256, 256, 0, stream>>>(batch, gstart, n);

    // encoder (writes bf16 h and fp8 shadow with +eb folded)
    {
        int threads = n * 32;
        enc_kernel<<<(threads + 255) / 256, 256, 0, stream>>>(x, enc_w, enc_b, edge_b, hb, h8, n);
    }

    // fused layers: gather + MFMA MLP in one kernel per layer
    for (int l = 0; l < NLAYERS; ++l) {
        layer_kernel<<<(n + TMM - 1) / TMM, 256, 0, stream>>>(
            hb, h8, start, sedge, edge_w, eps, l,
            w1f + (size_t)l * 16384, mlp_b1 + (size_t)l * H,
            w2f + (size_t)l * 16384,
            scb + (size_t)l * H, shb + (size_t)l * H,
            (l == 0) ? h8 : (unsigned char*)nullptr, edge_b, n);
    }

    pool_kernel<<<dim3(NGRAPH, 8), 256, 0, stream>>>(hb, gstart, sums);
    cls_kernel<<<NGRAPH, 64, 0, stream>>>(sums, gstart, cls_w1, cls_b1, cls_w2, cls_b2, out);
}

// Round 20
// 364.177 us; speedup vs baseline: 1.0702x; 1.0702x over previous
//
#include <hip/hip_runtime.h>
#include <hip/hip_bf16.h>

#define H 128
#define NGRAPH 64
#define NLAYERS 2
#define TMM 64          // rows per MLP block
#define TP 136          // LDS row stride in bf16 (pad 8)
#define BSH 8           // bucket shift: 256 nodes per bucket
#define MAXB 512        // max buckets (n <= 131072)

typedef short short8 __attribute__((ext_vector_type(8)));
typedef float floatx4 __attribute__((ext_vector_type(4)));
typedef float floatx2 __attribute__((ext_vector_type(2)));

static __device__ __forceinline__ unsigned short f2bf(float v) {
    __hip_bfloat16 b = __float2bfloat16(v);
    return *(unsigned short*)&b;
}
static __device__ __forceinline__ float bf2f(unsigned short u) {
    return __uint_as_float(((unsigned int)u) << 16);
}
// pack 4 f32 -> 4 fp8(e4m3) bytes
static __device__ __forceinline__ int pack4_fp8(float a, float b, float c, float d) {
    int p = __builtin_amdgcn_cvt_pk_fp8_f32(a, b, 0, false);
    p = __builtin_amdgcn_cvt_pk_fp8_f32(c, d, p, true);
    return p;
}

// ------- encoder: h = bf16(x*w+b); fp8 shadow h8 = fp8(h + edge_bias) -------
__global__ void enc_kernel(const float* __restrict__ x, const float* __restrict__ w,
                           const float* __restrict__ b, const float* __restrict__ eb,
                           unsigned short* __restrict__ h,
                           unsigned char* __restrict__ h8, int n) {
    int t = blockIdx.x * blockDim.x + threadIdx.x;
    int i = t >> 5;            // node
    int c = (t & 31) << 2;     // feature*4
    if (i >= n) return;
    float xv = x[i];
    float4 wv = *(const float4*)(w + c);
    float4 bv = *(const float4*)(b + c);
    float4 ev = *(const float4*)(eb + c);
    float4 o;
    o.x = xv * wv.x + bv.x;
    o.y = xv * wv.y + bv.y;
    o.z = xv * wv.z + bv.z;
    o.w = xv * wv.w + bv.w;
    ushort4 ob;
    ob.x = f2bf(o.x); ob.y = f2bf(o.y); ob.z = f2bf(o.z); ob.w = f2bf(o.w);
    *(ushort4*)(h + (size_t)i * H + c) = ob;
    *(int*)(h8 + (size_t)i * H + c) =
        pack4_fp8(o.x + ev.x, o.y + ev.y, o.z + ev.z, o.w + ev.w);
}

// ------- prep: weights to bf16 fragment-major + BN fold (merged) -------
__global__ void prep_kernel(const float* __restrict__ w1, const float* __restrict__ w2,
                            unsigned short* __restrict__ w1f, unsigned short* __restrict__ w2f,
                            const float* __restrict__ b2, const float* __restrict__ g,
                            const float* __restrict__ bt, const float* __restrict__ mn,
                            const float* __restrict__ vr,
                            float* __restrict__ scb, float* __restrict__ shb) {
    int idx = blockIdx.x * blockDim.x + threadIdx.x;   // 2*128*128
    int l = idx >> 14;
    int r = idx & 16383;
    int nn = r >> 7;      // output col = B row
    int kk = r & 127;     // k index
    int ct = nn >> 4, m = nn & 15;
    int kbi = kk >> 5, q = (kk >> 3) & 3, j = kk & 7;
    int fo = l * 16384 + ct * 2048 + kbi * 512 + (q * 16 + m) * 8 + j;
    w1f[fo] = f2bf(w1[(size_t)l * 16384 + kk * 128 + nn]);
    w2f[fo] = f2bf(w2[(size_t)l * 16384 + kk * 128 + nn]);
    if (idx < NLAYERS * H) {
        float sc = g[idx] * rsqrtf(vr[idx] + 1e-5f);
        scb[idx] = sc;
        shb[idx] = (b2[idx] - mn[idx]) * sc + bt[idx];
    }
}

// ---- bucket histogram: LDS-aggregated counts of edges per 256-node bucket ----
__global__ __launch_bounds__(256) void histB_kernel(const int* __restrict__ ei,
                                                    int* __restrict__ bcnt, int ne) {
    __shared__ int hist[MAXB];
    const int t = threadIdx.x;
    const int e0 = blockIdx.x * 4096;
    for (int k = t; k < MAXB; k += 256) hist[k] = 0;
    __syncthreads();
    #pragma unroll
    for (int k = 0; k < 16; ++k) {
        int e = e0 + k * 256 + t;
        if (e < ne) atomicAdd(&hist[ei[ne + e] >> BSH], 1);
    }
    __syncthreads();
    for (int b = t; b < MAXB; b += 256) {
        int c = hist[b];
        if (c > 0) atomicAdd(&bcnt[b], c);
    }
}

// ---- bucket scan: exclusive prefix over <=512 bucket counts (one block) ----
__global__ __launch_bounds__(256) void scanB_kernel(const int* __restrict__ bcnt,
                                                    int* __restrict__ bstart,
                                                    int* __restrict__ start,
                                                    int nbuck, int n, int ne) {
    __shared__ int wsum[4];
    const int t = threadIdx.x;
    const int lane = t & 63;
    const int wid = t >> 6;
    int i0 = 2 * t, i1 = 2 * t + 1;
    int v0 = (i0 < nbuck) ? bcnt[i0] : 0;
    int v1 = (i1 < nbuck) ? bcnt[i1] : 0;
    int s = v0 + v1;
    int incl = s;
    #pragma unroll
    for (int off = 1; off < 64; off <<= 1) {
        int u = __shfl_up(incl, off, 64);
        if (lane >= off) incl += u;
    }
    if (lane == 63) wsum[wid] = incl;
    __syncthreads();
    int woff = 0;
    #pragma unroll
    for (int k = 0; k < 4; ++k) if (k < wid) woff += wsum[k];
    int excl = woff + incl - s;
    if (i0 < nbuck) bstart[i0] = excl;
    if (i1 < nbuck) bstart[i1] = excl + v0;
    if (t == 0) { bstart[nbuck] = ne; start[n] = ne; }
}

// ---- sort phase A: bin edges into buckets, block-coalesced runs ----
// entry: x = src, y = (attr_bf16 << 16) | local_dst(8b)
__global__ __launch_bounds__(256) void binA_kernel(
    const int* __restrict__ ei, const float* __restrict__ ea,
    const int* __restrict__ bstart, int* __restrict__ bcursor,
    int2* __restrict__ sedge2, int ne, int nbuck) {
    __shared__ int hist[MAXB];
    __shared__ int gpos[MAXB];
    const int t = threadIdx.x;
    const int e0 = blockIdx.x * 4096;
    for (int k = t; k < MAXB; k += 256) hist[k] = 0;
    __syncthreads();
    int dsts[16];
    #pragma unroll
    for (int k = 0; k < 16; ++k) {
        int e = e0 + k * 256 + t;
        int d = (e < ne) ? ei[ne + e] : -1;
        dsts[k] = d;
        if (d >= 0) atomicAdd(&hist[d >> BSH], 1);
    }
    __syncthreads();
    for (int b = t; b < nbuck; b += 256) {
        int c = hist[b];
        gpos[b] = (c > 0) ? (bstart[b] + atomicAdd(&bcursor[b], c)) : 0;
    }
    __syncthreads();
    for (int k = t; k < MAXB; k += 256) hist[k] = 0;   // reuse as local cursor
    __syncthreads();
    #pragma unroll
    for (int k = 0; k < 16; ++k) {
        int d = dsts[k];
        if (d >= 0) {
            int e = e0 + k * 256 + t;
            int b = d >> BSH;
            int idx = atomicAdd(&hist[b], 1);
            int2 p;
            p.x = ei[e];
            p.y = ((int)f2bf(ea[e]) << 16) | (d & ((1 << BSH) - 1));
            sedge2[gpos[b] + idx] = p;
        }
    }
}

// ---- sort phase B: per-bucket node layout + exact scatter (one block/bucket) ----
// Derives per-node starts locally (LDS hist+scan), writes global start[],
// then scatters edges to exact node positions. Strips local_dst from y.
__global__ __launch_bounds__(256) void binB_kernel(
    const int2* __restrict__ sedge2, const int* __restrict__ bstart,
    int2* __restrict__ sedge, int* __restrict__ start, int n) {
    __shared__ int nhist[1 << BSH];
    __shared__ int nstart_s[1 << BSH];
    __shared__ int wsum[4];
    const int node0 = blockIdx.x << BSH;
    const int t = threadIdx.x;
    const int lane = t & 63;
    const int wid = t >> 6;
    nhist[t] = 0;
    __syncthreads();
    int s0 = bstart[blockIdx.x];
    int s1 = bstart[blockIdx.x + 1];
    for (int i = s0 + t; i < s1; i += 256)
        atomicAdd(&nhist[sedge2[i].y & ((1 << BSH) - 1)], 1);
    __syncthreads();
    // LDS scan of 256 node counts
    int v = nhist[t];
    int incl = v;
    #pragma unroll
    for (int off = 1; off < 64; off <<= 1) {
        int u = __shfl_up(incl, off, 64);
        if (lane >= off) incl += u;
    }
    if (lane == 63) wsum[wid] = incl;
    __syncthreads();
    int woff = 0;
    #pragma unroll
    for (int k = 0; k < 4; ++k) if (k < wid) woff += wsum[k];
    int excl = woff + incl - v;
    nstart_s[t] = excl;
    if (node0 + t < n) start[node0 + t] = s0 + excl;
    nhist[t] = 0;       // reuse as per-node cursor
    __syncthreads();
    for (int i = s0 + t; i < s1; i += 256) {
        int2 p = sedge2[i];
        int ld = p.y & ((1 << BSH) - 1);
        int idx = atomicAdd(&nhist[ld], 1);
        p.y = (int)((unsigned)p.y & 0xffff0000u);   // attr bf16 only
        sedge[s0 + nstart_s[ld] + idx] = p;
    }
}

// ---- segment-reduce gather: z[i] = (1+eps)*h[i] + sum_j relu(h8[src_j]+a*ew) ----
__global__ __launch_bounds__(256) void aggregate_kernel(
    const unsigned short* __restrict__ h, const unsigned char* __restrict__ h8,
    const int* __restrict__ start, const int2* __restrict__ sedge,
    const float* __restrict__ ew,
    const float* __restrict__ epsp, int layer,
    unsigned short* __restrict__ z, int n) {
    int node = (blockIdx.x * blockDim.x + threadIdx.x) >> 6;
    int lane = threadIdx.x & 63;
    if (node >= n) return;
    const unsigned c = (unsigned)lane << 1;
    float2 wv = *(const float2*)(ew + c);
    float2 acc = make_float2(0.f, 0.f);
    int s0 = start[node], s1 = start[node + 1];
    int j = s0;
    // 16-deep full chunks: no clamp, no mask, 16 gathers in flight
    for (; j + 16 <= s1; j += 16) {
        int2 e[16];
        unsigned short v8[16];
        #pragma unroll
        for (int k = 0; k < 16; ++k) e[k] = sedge[j + k];
        #pragma unroll
        for (int k = 0; k < 16; ++k)
            v8[k] = *(const unsigned short*)(h8 + (((unsigned)e[k].x << 7) + c));
        #pragma unroll
        for (int k = 0; k < 16; ++k) {
            float a = __int_as_float(e[k].y);
            floatx2 hv = __builtin_amdgcn_cvt_pk_f32_fp8((int)v8[k], false);
            acc.x += fmaxf(fmaf(a, wv.x, hv.x), 0.f);
            acc.y += fmaxf(fmaf(a, wv.y, hv.y), 0.f);
        }
    }
    // one 8-deep full chunk
    if (j + 8 <= s1) {
        int2 e[8];
        unsigned short v8[8];
        #pragma unroll
        for (int k = 0; k < 8; ++k) e[k] = sedge[j + k];
        #pragma unroll
        for (int k = 0; k < 8; ++k)
            v8[k] = *(const unsigned short*)(h8 + (((unsigned)e[k].x << 7) + c));
        #pragma unroll
        for (int k = 0; k < 8; ++k) {
            float a = __int_as_float(e[k].y);
            floatx2 hv = __builtin_amdgcn_cvt_pk_f32_fp8((int)v8[k], false);
            acc.x += fmaxf(fmaf(a, wv.x, hv.x), 0.f);
            acc.y += fmaxf(fmaf(a, wv.y, hv.y), 0.f);
        }
        j += 8;
    }
    // single masked tail chunk
    if (j < s1) {
        int2 e[8];
        unsigned short v8[8];
        #pragma unroll
        for (int k = 0; k < 8; ++k) {
            int idx = j + k;
            e[k] = sedge[idx < s1 ? idx : (s1 - 1)];
        }
        #pragma unroll
        for (int k = 0; k < 8; ++k)
            v8[k] = *(const unsigned short*)(h8 + (((unsigned)e[k].x << 7) + c));
        #pragma unroll
        for (int k = 0; k < 8; ++k) {
            float valid = (j + k < s1) ? 1.f : 0.f;
            float a = __int_as_float(e[k].y);
            floatx2 hv = __builtin_amdgcn_cvt_pk_f32_fp8((int)v8[k], false);
            acc.x += valid * fmaxf(fmaf(a, wv.x, hv.x), 0.f);
            acc.y += valid * fmaxf(fmaf(a, wv.y, hv.y), 0.f);
        }
    }
    float ev = 1.0f + epsp[layer];
    ushort2 hv = *(const ushort2*)(h + (size_t)node * H + c);
    ushort2 p;
    p.x = f2bf(fmaf(ev, bf2f(hv.x), acc.x));
    p.y = f2bf(fmaf(ev, bf2f(hv.y), acc.y));
    *(ushort2*)(z + (size_t)node * H + c) = p;
}

// ---- MFMA node MLP: h = bf16(relu(BN(relu(z@w1+b1)@w2+b2))), bf16 in/out ----
// All operand paths coalesced (LDS-staged, wave-private, no barriers).
// Layer 0 additionally emits the fp8 shadow h8 = fp8(h + eb) (fused cast).
__global__ __launch_bounds__(256) void mfma_mlp_kernel(
    unsigned short* __restrict__ h, const unsigned short* __restrict__ z,
    const unsigned short* __restrict__ w1f, const float* __restrict__ b1,
    const unsigned short* __restrict__ w2f,
    const float* __restrict__ scb, const float* __restrict__ shb,
    unsigned char* __restrict__ h8out, const float* __restrict__ eb, int n) {
    __shared__ unsigned short zs[4][16 * TP];   // per-wave z tile / output tile
    __shared__ unsigned short ts[4][16 * TP];   // per-wave t tile
    const int tid = threadIdx.x;
    const int wid = tid >> 6;
    const int lane = tid & 63;
    const int m = lane & 15;     // A row within 16 / B col
    const int q = lane >> 4;     // quad
    const int row0 = blockIdx.x * TMM + wid * 16;

    // ---- stage 16 z rows, coalesced (wave-private, no barrier) ----
    unsigned short* zw = zs[wid];
    {
        const unsigned short* zg = z + (size_t)row0 * H;
        #pragma unroll
        for (int i = 0; i < 4; ++i) {
            int idx = i * 64 + lane;       // 0..255
            int r = idx >> 4;              // 0..15
            int c8 = (idx & 15) << 3;      // 0..120
            short8 v = (short8)(0);
            if (row0 + r < n) v = *(const short8*)(zg + r * H + c8);
            *(short8*)(zw + r * TP + c8) = v;
        }
    }

    // ---------- GEMM1: t = relu(z @ w1 + b1) ----------
    floatx4 acc[8];
    #pragma unroll
    for (int ct = 0; ct < 8; ++ct) acc[ct] = (floatx4)(0.f);

    #pragma unroll
    for (int kbi = 0; kbi < 4; ++kbi) {
        short8 a = *(const short8*)(zw + m * TP + kbi * 32 + q * 8);
        #pragma unroll
        for (int ct = 0; ct < 8; ++ct) {
            short8 b = *(const short8*)(w1f + ct * 2048 + kbi * 512 + lane * 8);
            acc[ct] = __builtin_amdgcn_mfma_f32_16x16x32_bf16(a, b, acc[ct], 0, 0, 0);
        }
    }
    unsigned short* tw = ts[wid];
    #pragma unroll
    for (int ct = 0; ct < 8; ++ct) {
        float bb = b1[ct * 16 + m];
        #pragma unroll
        for (int r = 0; r < 4; ++r) {
            float v = fmaxf(acc[ct][r] + bb, 0.f);
            tw[(q * 4 + r) * TP + ct * 16 + m] = f2bf(v);
        }
    }

    // ---------- GEMM2: z2 = t @ w2, then folded BN (sc,sh) + relu ----------
    floatx4 acc2[8];
    #pragma unroll
    for (int ct = 0; ct < 8; ++ct) acc2[ct] = (floatx4)(0.f);

    #pragma unroll
    for (int kbi = 0; kbi < 4; ++kbi) {
        short8 a = *(const short8*)(tw + m * TP + kbi * 32 + q * 8);
        #pragma unroll
        for (int ct = 0; ct < 8; ++ct) {
            short8 b = *(const short8*)(w2f + ct * 2048 + kbi * 512 + lane * 8);
            acc2[ct] = __builtin_amdgcn_mfma_f32_16x16x32_bf16(a, b, acc2[ct], 0, 0, 0);
        }
    }
    // epilogue2: stage C into wave-private LDS tile (reuse zw), coalesced store
    #pragma unroll
    for (int ct = 0; ct < 8; ++ct) {
        int col = ct * 16 + m;
        float scv = scb[col];
        float shv = shb[col];
        #pragma unroll
        for (int r = 0; r < 4; ++r) {
            float v = fmaxf(fmaf(acc2[ct][r], scv, shv), 0.f);
            zw[(q * 4 + r) * TP + col] = f2bf(v);
        }
    }
    {
        unsigned short* hg = h + (size_t)row0 * H;
        #pragma unroll
        for (int i = 0; i < 4; ++i) {
            int idx = i * 64 + lane;
            int r = idx >> 4;
            int c8 = (idx & 15) << 3;
            if (row0 + r < n)
                *(short8*)(hg + r * H + c8) = *(const short8*)(zw + r * TP + c8);
        }
    }
    // fused cast (layer 0 only): h8 = fp8(h + eb), coalesced 8 B/lane
    if (h8out) {
        unsigned char* h8g = h8out + (size_t)row0 * H;
        #pragma unroll
        for (int i = 0; i < 4; ++i) {
            int idx = i * 64 + lane;
            int r = idx >> 4;
            int c8 = (idx & 15) << 3;
            if (row0 + r < n) {
                const unsigned short* src = zw + r * TP + c8;
                float4 e0 = *(const float4*)(eb + c8);
                float4 e1 = *(const float4*)(eb + c8 + 4);
                int2 pk;
                pk.x = pack4_fp8(bf2f(src[0]) + e0.x, bf2f(src[1]) + e0.y,
                                 bf2f(src[2]) + e0.z, bf2f(src[3]) + e0.w);
                pk.y = pack4_fp8(bf2f(src[4]) + e1.x, bf2f(src[5]) + e1.y,
                                 bf2f(src[6]) + e1.z, bf2f(src[7]) + e1.w);
                *(int2*)(h8g + r * H + c8) = pk;
            }
        }
    }
}

// ---- graph boundaries from sorted batch: gstart[g] = first node of graph g ----
__global__ void gbound_kernel(const int* __restrict__ batch, int* __restrict__ gstart, int n) {
    int i = blockIdx.x * blockDim.x + threadIdx.x;
    if (i >= n) return;
    int b = batch[i];
    if (i == 0) {
        for (int g = 0; g <= b; ++g) gstart[g] = 0;
    } else {
        int p = batch[i - 1];
        for (int g = p + 1; g <= b; ++g) gstart[g] = i;
    }
    if (i == n - 1) {
        for (int g = b + 1; g <= NGRAPH; ++g) gstart[g] = n;
    }
}

// ---- global mean pool: segmented gather of bf16 h, LDS reduce, few atomics ----
__global__ __launch_bounds__(256) void pool_kernel(const unsigned short* __restrict__ h,
                                                   const int* __restrict__ gstart,
                                                   float* __restrict__ sums) {
    __shared__ float4 buf[8][32];
    const int g = blockIdx.x;       // graph
    const int split = blockIdx.y;   // 0..7
    const int t = threadIdx.x;
    const int c32 = t & 31;
    const int c = c32 << 2;
    const int r = t >> 5;           // 0..7
    int s0 = gstart[g], s1 = gstart[g + 1];
    int len = s1 - s0;
    int chunk = (len + 7) >> 3;
    int a = s0 + split * chunk;
    int b = min(a + chunk, s1);
    float4 acc = make_float4(0.f, 0.f, 0.f, 0.f);
    for (int i = a + r; i < b; i += 8) {
        ushort4 v = *(const ushort4*)(h + (size_t)i * H + c);
        acc.x += bf2f(v.x); acc.y += bf2f(v.y); acc.z += bf2f(v.z); acc.w += bf2f(v.w);
    }
    buf[r][c32] = acc;
    __syncthreads();
    if (r == 0) {
        float4 s = buf[0][c32];
        #pragma unroll
        for (int k = 1; k < 8; ++k) {
            float4 v = buf[k][c32];
            s.x += v.x; s.y += v.y; s.z += v.z; s.w += v.w;
        }
        float* sp = sums + (size_t)g * H + c;
        atomicAdd(sp + 0, s.x);
        atomicAdd(sp + 1, s.y);
        atomicAdd(sp + 2, s.z);
        atomicAdd(sp + 3, s.w);
    }
}

// ---------------- classifier: sigmoid(relu(g@w1+b1)@w2+b2) ----------------
__global__ void cls_kernel(const float* __restrict__ sums, const int* __restrict__ gstart,
                           const float* __restrict__ w1, const float* __restrict__ b1,
                           const float* __restrict__ w2, const float* __restrict__ b2,
                           float* __restrict__ out) {
    int g = blockIdx.x;     // 64 graphs
    int m = threadIdx.x;    // 64 mids
    float cnt = (float)(gstart[g + 1] - gstart[g]);
    float inv = 1.0f / fmaxf(cnt, 1.0f);
    float acc = 0.f;
    for (int k = 0; k < H; ++k) {
        float gk = sums[(size_t)g * H + k] * inv;
        acc += gk * w1[(size_t)k * 64 + m];
    }
    float tm = fmaxf(acc + b1[m], 0.f);
    float p = tm * w2[m];
    #pragma unroll
    for (int off = 32; off > 0; off >>= 1) p += __shfl_down(p, off, 64);
    if (m == 0) out[g] = 1.f / (1.f + expf(-(p + b2[0])));
}

extern "C" void kernel_launch(void* const* d_in, const int* in_sizes, int n_in,
                              void* d_out, int out_size, void* d_ws, size_t ws_size,
                              hipStream_t stream) {
    const float* x      = (const float*)d_in[0];
    const int*   ei     = (const int*)d_in[1];
    const float* ea     = (const float*)d_in[2];
    const int*   batch  = (const int*)d_in[3];
    const float* enc_w  = (const float*)d_in[4];
    const float* enc_b  = (const float*)d_in[5];
    const float* edge_w = (const float*)d_in[6];
    const float* edge_b = (const float*)d_in[7];
    const float* eps    = (const float*)d_in[8];
    const float* mlp_w1 = (const float*)d_in[9];
    const float* mlp_b1 = (const float*)d_in[10];
    const float* mlp_w2 = (const float*)d_in[11];
    const float* mlp_b2 = (const float*)d_in[12];
    const float* bn_g   = (const float*)d_in[13];
    const float* bn_b   = (const float*)d_in[14];
    const float* bn_m   = (const float*)d_in[15];
    const float* bn_v   = (const float*)d_in[16];
    const float* cls_w1 = (const float*)d_in[17];
    const float* cls_b1 = (const float*)d_in[18];
    const float* cls_w2 = (const float*)d_in[19];
    const float* cls_b2 = (const float*)d_in[20];
    float* out = (float*)d_out;

    const int n = in_sizes[0];        // 100000
    const int ne = in_sizes[2];       // 1600000
    const int nbuck = (n + (1 << BSH) - 1) >> BSH;  // 256-node buckets

    // workspace layout (regions kept 16B-aligned).
    // sums, bcnt, bcursor are CONTIGUOUS so one memset zeroes all three.
    unsigned short* hb  = (unsigned short*)d_ws;                    // N*H bf16
    unsigned short* zb  = hb + (size_t)n * H;                       // N*H bf16
    unsigned char* h8   = (unsigned char*)(zb + (size_t)n * H);     // N*H fp8
    float* sums         = (float*)(h8 + (size_t)n * H);             // G*H
    int*   bcnt         = (int*)(sums + (size_t)NGRAPH * H);        // MAXB
    int*   bcursor      = bcnt + MAXB;                              // MAXB
    int*   bstart       = bcursor + MAXB;                           // MAXB+4
    int*   gstart       = bstart + MAXB + 4;                        // G+4
    int*   start        = gstart + NGRAPH + 4;                      // N+4
    float* scb          = (float*)(start + n + 4);                  // 2*128
    float* shb          = scb + NLAYERS * H;                        // 2*128
    unsigned short* w1f = (unsigned short*)(shb + NLAYERS * H);     // 2*128*128
    unsigned short* w2f = w1f + 2 * 16384;                          // 2*128*128
    int2*  sedge2       = (int2*)(w2f + 2 * 16384);                 // E (binned)
    int2*  sedge        = sedge2 + ne;                              // E (sorted)

    // one memset covers sums + bcnt + bcursor (contiguous)
    hipMemsetAsync(sums, 0, ((size_t)NGRAPH * H + 2 * MAXB) * sizeof(int), stream);

    // weight prep (bf16 fragment-major) + BN fold — once per call
    prep_kernel<<<128, 256, 0, stream>>>(mlp_w1, mlp_w2, w1f, w2f,
                                         mlp_b2, bn_g, bn_b, bn_m, bn_v, scb, shb);

    // ---- bucket-granular counting sort of edges by dst ----
    histB_kernel<<<(ne + 4095) / 4096, 256, 0, stream>>>(ei, bcnt, ne);
    scanB_kernel<<<1, 256, 0, stream>>>(bcnt, bstart, start, nbuck, n, ne);
    binA_kernel<<<(ne + 4095) / 4096, 256, 0, stream>>>(ei, ea, bstart, bcursor, sedge2, ne, nbuck);
    binB_kernel<<<nbuck, 256, 0, stream>>>(sedge2, bstart, sedge, start, n);

    // graph boundaries for pooling
    gbound_kernel<<<(n + 255) / 256, 256, 0, stream>>>(batch, gstart, n);

    // encoder (writes bf16 h and fp8 shadow with +eb folded)
    {
        int threads = n * 32;
        enc_kernel<<<(threads + 255) / 256, 256, 0, stream>>>(x, enc_w, enc_b, edge_b, hb, h8, n);
    }

    for (int l = 0; l < NLAYERS; ++l) {
        {
            int threads = n * 64;
            aggregate_kernel<<<(threads + 255) / 256, 256, 0, stream>>>(
                hb, h8, start, sedge, edge_w, eps, l, zb, n);
        }
        mfma_mlp_kernel<<<(n + TMM - 1) / TMM, 256, 0, stream>>>(
            hb, zb,
            w1f + (size_t)l * 16384, mlp_b1 + (size_t)l * H,
            w2f + (size_t)l * 16384,
            scb + (size_t)l * H, shb + (size_t)l * H,
            (l == 0) ? h8 : (unsigned char*)nullptr, edge_b, n);
    }

    pool_kernel<<<dim3(NGRAPH, 8), 256, 0, stream>>>(hb, gstart, sums);
    cls_kernel<<<NGRAPH, 64, 0, stream>>>(sums, gstart, cls_w1, cls_b1, cls_w2, cls_b2, out);
}